// Round 1
// baseline (171.968 us; speedup 1.0000x reference)
//
#include <hip/hip_runtime.h>

// RegL1Loss: out[b] = sum_{p,d} valid * |preds[b, idx] - val| / num_people[b]
// B=32, P=64, D=34, L=1048576. gts layout [B,P,D,3] = (val, idx, flag).
//
// One block per image b. 256 threads = 64 persons x 4 sub-threads.
// Per-person 4-lane shuffle reduce -> wave butterfly -> 4-wave LDS reduce.

#define B_ 32
#define P_ 64
#define D_ 34
#define L_ 1048576

__global__ __launch_bounds__(256) void reg_l1_kernel(
    const float* __restrict__ preds,
    const float* __restrict__ gts,
    float* __restrict__ out) {
  const int b   = blockIdx.x;
  const int tid = threadIdx.x;
  const int p   = tid >> 2;   // person 0..63
  const int sub = tid & 3;    // 0..3

  const float* pred_b = preds + (size_t)b * L_;
  const float* gt_p   = gts + (((size_t)b * P_ + p) * D_) * 3;

  float sum = 0.0f;
  int any = 0;
  // Each sub-thread handles dims sub, sub+4, ... (<= 9 iterations)
  for (int d = sub; d < D_; d += 4) {
    const float v    = gt_p[d * 3 + 0];
    const float fidx = gt_p[d * 3 + 1];
    const float flag = gt_p[d * 3 + 2];
    if (flag > 0.0f) {
      const int idx = (int)fidx;   // exact: randint < 2^24
      const float g = pred_b[idx];
      sum += fabsf(g - v);
      any = 1;
    }
  }

  // Reduce the 4-thread person group (groups are wave-aligned: 4 | 64).
  sum += __shfl_xor(sum, 1);
  sum += __shfl_xor(sum, 2);
  any |= __shfl_xor(any, 1);
  any |= __shfl_xor(any, 2);

  // Only sub==0 contributes its person's result to the wave reduction.
  float psum = (sub == 0) ? sum        : 0.0f;
  float pcnt = (sub == 0) ? (float)any : 0.0f;

  // Butterfly across the wave (16 persons per wave).
  for (int off = 4; off < 64; off <<= 1) {
    psum += __shfl_xor(psum, off);
    pcnt += __shfl_xor(pcnt, off);
  }

  // Cross-wave reduce (4 waves per block).
  __shared__ float s_sum[4];
  __shared__ float s_cnt[4];
  const int wave = tid >> 6;
  const int lane = tid & 63;
  if (lane == 0) {
    s_sum[wave] = psum;
    s_cnt[wave] = pcnt;
  }
  __syncthreads();
  if (tid == 0) {
    const float ts = s_sum[0] + s_sum[1] + s_sum[2] + s_sum[3];
    const float tc = s_cnt[0] + s_cnt[1] + s_cnt[2] + s_cnt[3];
    out[b] = ts / tc;   // >=1 valid per image guaranteed by setup
  }
}

extern "C" void kernel_launch(void* const* d_in, const int* in_sizes, int n_in,
                              void* d_out, int out_size, void* d_ws, size_t ws_size,
                              hipStream_t stream) {
  const float* preds = (const float*)d_in[0];  // [B, L]
  const float* gts   = (const float*)d_in[1];  // [B, P, D, 3]
  float* out = (float*)d_out;                  // [B]
  reg_l1_kernel<<<B_, 256, 0, stream>>>(preds, gts, out);
}

// Round 2
// 163.973 us; speedup vs baseline: 1.0488x; 1.0488x over previous
//
#include <hip/hip_runtime.h>

// RegL1Loss: out[b] = sum_{p,d} valid * |preds[b, idx[b,p,d]] - val| / num_people[b]
// B=32, P=64, D=34, L=1048576. gts layout [B,P,D,3] = (val, idx, flag).
//
// Latency-bound tiny problem: ~70K random 4B gathers + 835 KB sequential read.
// Strategy: maximize parallelism so every gather chain is depth-1.
//   Kernel 1: grid (16, 32) x 256 threads. One wave per person (lane = dim,
//             34 active lanes). Wave butterfly-reduce |pred-val|; person
//             validity via __ballot. Block reduces its 4 persons in LDS and
//             writes one (sum, cnt) partial pair to d_ws — deterministic
//             slots, no atomics, no zero-init needed.
//   Kernel 2: 32 blocks x 64 threads. Reduce 16 partials per image, divide.

#define B_ 32
#define P_ 64
#define D_ 34
#define L_ 1048576
#define GPB 4                      // persons (waves) per block
#define BLK_PER_IMG (P_ / GPB)     // 16

__global__ __launch_bounds__(256) void reg_l1_main(
    const float* __restrict__ preds,
    const float* __restrict__ gts,
    float* __restrict__ ws) {
  const int g    = blockIdx.x;            // person-group 0..15
  const int b    = blockIdx.y;            // image 0..31
  const int wave = threadIdx.x >> 6;      // 0..3
  const int lane = threadIdx.x & 63;
  const int p    = g * GPB + wave;        // person 0..63

  float contrib = 0.0f;
  int valid = 0;
  if (lane < D_) {
    const float* gt = gts + (((size_t)b * P_ + p) * D_ + lane) * 3;
    const float v    = gt[0];
    const float fidx = gt[1];
    const float flag = gt[2];
    if (flag > 0.0f) {
      const int idx = (int)fidx;          // exact: randint < 2^24
      contrib = fabsf(preds[(size_t)b * L_ + idx] - v);
      valid = 1;
    }
  }

  // Wave reduction: sum of contributions, any-valid via ballot.
  for (int off = 1; off < 64; off <<= 1) contrib += __shfl_xor(contrib, off);
  const unsigned long long bal = __ballot(valid);
  const float pcnt = (bal != 0ull) ? 1.0f : 0.0f;

  __shared__ float s_sum[GPB];
  __shared__ float s_cnt[GPB];
  if (lane == 0) {
    s_sum[wave] = contrib;
    s_cnt[wave] = pcnt;
  }
  __syncthreads();
  if (threadIdx.x == 0) {
    const float ts = s_sum[0] + s_sum[1] + s_sum[2] + s_sum[3];
    const float tc = s_cnt[0] + s_cnt[1] + s_cnt[2] + s_cnt[3];
    ws[b * BLK_PER_IMG + g] = ts;                        // partial sums
    ws[B_ * BLK_PER_IMG + b * BLK_PER_IMG + g] = tc;     // partial counts
  }
}

__global__ __launch_bounds__(64) void reg_l1_final(
    const float* __restrict__ ws,
    float* __restrict__ out) {
  const int b    = blockIdx.x;
  const int lane = threadIdx.x;   // 0..63
  float s = 0.0f, c = 0.0f;
  if (lane < BLK_PER_IMG) {
    s = ws[b * BLK_PER_IMG + lane];
    c = ws[B_ * BLK_PER_IMG + b * BLK_PER_IMG + lane];
  }
  for (int off = 1; off < BLK_PER_IMG; off <<= 1) {
    s += __shfl_xor(s, off);
    c += __shfl_xor(c, off);
  }
  if (lane == 0) out[b] = s / c;   // >=1 valid person guaranteed by setup
}

extern "C" void kernel_launch(void* const* d_in, const int* in_sizes, int n_in,
                              void* d_out, int out_size, void* d_ws, size_t ws_size,
                              hipStream_t stream) {
  const float* preds = (const float*)d_in[0];  // [B, L]
  const float* gts   = (const float*)d_in[1];  // [B, P, D, 3]
  float* out = (float*)d_out;                  // [B]
  float* ws  = (float*)d_ws;                   // 1024 floats used

  dim3 grid(BLK_PER_IMG, B_);
  reg_l1_main<<<grid, 256, 0, stream>>>(preds, gts, ws);
  reg_l1_final<<<B_, 64, 0, stream>>>(ws, out);
}